// Round 10
// baseline (567.329 us; speedup 1.0000x reference)
//
#include <hip/hip_runtime.h>
#include <math.h>

#define NB 256
#define SEQ 26
#define TOK (NB*SEQ)   // 6656
#define DIM 512

typedef unsigned short u16;
typedef __attribute__((ext_vector_type(8))) short short8_t;
typedef __attribute__((ext_vector_type(4))) float floatx4;

__device__ inline u16 f2bf(float f) {
    union { float f; unsigned u; } v; v.f = f;
    unsigned r = v.u + 0x7fffu + ((v.u >> 16) & 1u);
    return (u16)(r >> 16);
}
__device__ inline float bf2f(u16 u) {
    union { unsigned u; float f; } v; v.u = ((unsigned)u) << 16; return v.f;
}

__device__ __forceinline__ void gload_lds16(const u16* g, u16* l) {
    __builtin_amdgcn_global_load_lds((const __attribute__((address_space(1))) void*)g,
                                     (__attribute__((address_space(3))) void*)l, 16, 0, 0);
}

// ---------------------------------------------------------------------------
// One-shot prep: weight transposes (f32->bf16 [N][K]), conv_w pad-copy,
// cls rows, qkv bias concat, AND the per-batch question path (que_map).
// Grid 1313, block 256.
__global__ void prep_all(const float* __restrict__ q_w, const float* __restrict__ k_w,
                         const float* __restrict__ v_w, const float* __restrict__ final_w,
                         const float* __restrict__ ffn1_w, const float* __restrict__ ffn2_w,
                         const float* __restrict__ map_w, const float* __restrict__ conv_w,
                         const float* __restrict__ q_b, const float* __restrict__ k_b,
                         const float* __restrict__ v_b, const float* __restrict__ cls,
                         const float* __restrict__ qst, const float* __restrict__ qrep_w,
                         const float* __restrict__ qrep_b, const float* __restrict__ map_b,
                         u16* __restrict__ qkvT, u16* __restrict__ finT,
                         u16* __restrict__ f1T, u16* __restrict__ f2T,
                         u16* __restrict__ mapT, u16* __restrict__ cwT,
                         float* __restrict__ qkvb, u16* __restrict__ emb,
                         float* __restrict__ quem) {
    __shared__ float lds[64][65];
    __shared__ float que[256];
    int blk = blockIdx.x;
    int t = threadIdx.x;
    if (blk < 544) {
        const float* W; u16* Wt; int K, N, tbase;
        if (blk < 64)       { W = q_w;     Wt = qkvT;            K = 512;  N = 512;  tbase = 0;   }
        else if (blk < 128) { W = k_w;     Wt = qkvT + 512*512;  K = 512;  N = 512;  tbase = 64;  }
        else if (blk < 192) { W = v_w;     Wt = qkvT + 1024*512; K = 512;  N = 512;  tbase = 128; }
        else if (blk < 256) { W = final_w; Wt = finT;            K = 512;  N = 512;  tbase = 192; }
        else if (blk < 384) { W = ffn1_w;  Wt = f1T;             K = 512;  N = 1024; tbase = 256; }
        else if (blk < 512) { W = ffn2_w;  Wt = f2T;             K = 1024; N = 512;  tbase = 384; }
        else                { W = map_w;   Wt = mapT;            K = 256;  N = 512;  tbase = 512; }
        int tloc = blk - tbase;
        int ntn = N >> 6;
        int n0 = (tloc % ntn) * 64, k0 = (tloc / ntn) * 64;
        int j = t & 63, i0 = t >> 6;
        #pragma unroll
        for (int p = 0; p < 16; ++p) {
            int i = i0*16 + p;
            lds[i][j] = W[(size_t)(k0+i)*N + n0 + j];
        }
        __syncthreads();
        int i2 = t & 63, j0 = t >> 6;
        #pragma unroll
        for (int p = 0; p < 16; ++p) {
            int j2 = j0*16 + p;
            Wt[(size_t)(n0+j2)*K + k0 + i2] = f2bf(lds[i2][j2]);
        }
    } else if (blk < 800) {
        int oc = blk - 544;
        for (int jj = t; jj < 704; jj += 256)
            cwT[(size_t)oc*704 + jj] = (jj < 675) ? f2bf(conv_w[(size_t)oc*675 + jj]) : (u16)0;
    } else if (blk < 1056) {
        int b = blk - 800;  // cls row for batch b
        emb[(size_t)(b*SEQ)*256 + t] = f2bf(cls[t]);
    } else if (blk == 1056) {
        for (int jj = t; jj < 1536; jj += 256)
            qkvb[jj] = jj < 512 ? q_b[jj] : (jj < 1024 ? k_b[jj-512] : v_b[jj-1024]);
    } else {
        int b = blk - 1057;  // question path for batch b
        float acc = qrep_b[t];
        for (int j = 0; j < 18; ++j) acc += qst[b*18 + j] * qrep_w[j*256 + t];
        que[t] = acc;
        __syncthreads();
        for (int n = t; n < DIM; n += 256) {
            float a2 = map_b[n];
            for (int k = 0; k < 256; ++k) a2 += que[k] * map_w[(256 + k)*DIM + n];
            quem[b*DIM + n] = a2;
        }
    }
}

// ---------------------------------------------------------------------------
// im2col: P[(b*25+pos)][j] bf16, K padded to 704
__global__ void im2col_kernel(const float* __restrict__ img, u16* __restrict__ P) {
    int ri = blockIdx.x;               // 0..6399
    int b = ri / 25, pos = ri % 25, ph = pos/5, pw = pos%5;
    for (int j = threadIdx.x; j < 704; j += 256) {
        float v = 0.f;
        if (j < 675) {
            int c = j / 225, rem = j % 225, kh = rem/15, kw = rem%15;
            v = img[(size_t)((b*3+c)*75 + ph*15 + kh)*75 + pw*15 + kw];
        }
        P[(size_t)ri*704 + j] = f2bf(v);
    }
}

// ---------------------------------------------------------------------------
// bf16 MFMA GEMM: C[M,N] = op(A[M,K] @ B + bias)*alpha [+res],  B given as Bt[N,K].
// BM x 128 tile (BM=128 or 64), BK=64, 512 threads (8 waves, 2x4).
// Double-buffered LDS; global_load_lds width=16; linear LDS dest with
// PRE-SWIZZLED global source (ch' = ch ^ (row&7)); ds_read applies same XOR.
// RESMODE: 0 none, 1 +res[row*N+col], 2 +res[(row/26)*N+col],
//          3 conv->emb: out row b*26+1+pos (+pe), bf16.
template<int BM, int RESMODE, int RELU, int OUTBF>
__global__ __launch_bounds__(512) void mfma_gemm(const u16* __restrict__ A, const u16* __restrict__ Bt,
                          const float* __restrict__ bias, const float* __restrict__ res,
                          void* __restrict__ Cout, int M, int N, int K, float alpha) {
    constexpr int MI  = BM / 32;   // acc row-tiles per wave
    constexpr int ALD = BM / 64;   // A gloads per thread
    __shared__ __align__(16) u16 As[2][BM*64];
    __shared__ __align__(16) u16 Bs[2][128*64];
    const int tid = threadIdx.x;
    const int lane = tid & 63;
    const int w = tid >> 6;             // 0..7
    const int wr = (w >> 2) * (MI*16);
    const int wc = (w & 3) * 32;
    const int bm = blockIdx.y * BM, bn = blockIdx.x * 128;

    floatx4 acc[MI][2];
    #pragma unroll
    for (int mi = 0; mi < MI; ++mi)
        #pragma unroll
        for (int ni = 0; ni < 2; ++ni)
            acc[mi][ni] = (floatx4){0.f,0.f,0.f,0.f};

    // staging addresses (loop-invariant)
    const u16* aptr[ALD];
    int aidx[ALD];
    #pragma unroll
    for (int s = 0; s < ALD; ++s) {
        int idx = s*512 + tid;
        int row = idx >> 3, ch = (idx & 7) ^ (row & 7);
        aptr[s] = &A[(size_t)(bm+row)*K + ch*8];
        aidx[s] = idx;
    }
    const u16* bptr[2];
    int bidx[2];
    #pragma unroll
    for (int s = 0; s < 2; ++s) {
        int idx = s*512 + tid;
        int row = idx >> 3, ch = (idx & 7) ^ (row & 7);
        bptr[s] = &Bt[(size_t)(bn+row)*K + ch*8];
        bidx[s] = idx;
    }

    const int nt = K >> 6;
    // prologue: stage tile 0 into buf 0
    #pragma unroll
    for (int s = 0; s < ALD; ++s) gload_lds16(aptr[s], &As[0][aidx[s]*8]);
    #pragma unroll
    for (int s = 0; s < 2; ++s)   gload_lds16(bptr[s], &Bs[0][bidx[s]*8]);
    __syncthreads();

    for (int t = 0; t < nt; ++t) {
        const int cur = t & 1;
        if (t + 1 < nt) {   // prefetch next tile into other buffer (overlaps MFMA)
            int off = (t + 1) << 6;
            #pragma unroll
            for (int s = 0; s < ALD; ++s) gload_lds16(aptr[s] + off, &As[cur^1][aidx[s]*8]);
            #pragma unroll
            for (int s = 0; s < 2; ++s)   gload_lds16(bptr[s] + off, &Bs[cur^1][bidx[s]*8]);
        }
        #pragma unroll
        for (int kk = 0; kk < 2; ++kk) {
            int ch2 = kk*4 + (lane >> 4);
            short8_t af[MI], bf[2];
            #pragma unroll
            for (int mi = 0; mi < MI; ++mi) {
                int row = wr + mi*16 + (lane & 15);
                af[mi] = *(const short8_t*)&As[cur][row*64 + ((ch2 ^ (row & 7))*8)];
            }
            #pragma unroll
            for (int ni = 0; ni < 2; ++ni) {
                int rowb = wc + ni*16 + (lane & 15);
                bf[ni] = *(const short8_t*)&Bs[cur][rowb*64 + ((ch2 ^ (rowb & 7))*8)];
            }
            #pragma unroll
            for (int mi = 0; mi < MI; ++mi)
                #pragma unroll
                for (int ni = 0; ni < 2; ++ni)
                    acc[mi][ni] = __builtin_amdgcn_mfma_f32_16x16x32_bf16(
                        af[mi], bf[ni], acc[mi][ni], 0, 0, 0);
        }
        __syncthreads();   // drains prefetch vmcnt + all lgkm; next tile ready
    }

    #pragma unroll
    for (int mi = 0; mi < MI; ++mi) {
        #pragma unroll
        for (int ni = 0; ni < 2; ++ni) {
            int col = bn + wc + ni*16 + (lane & 15);
            float bv = bias ? bias[col] : 0.0f;
            #pragma unroll
            for (int r = 0; r < 4; ++r) {
                int row = bm + wr + mi*16 + (lane >> 4)*4 + r;
                float v = (acc[mi][ni][r] + bv) * alpha;
                if (RELU) v = fmaxf(v, 0.f);
                if (RESMODE == 1)      v += res[(size_t)row*N + col];
                else if (RESMODE == 2) v += res[(size_t)(row/SEQ)*N + col];
                if (RESMODE == 3) {
                    // conv output row = b*25+pos -> emb row b*26+1+pos, plus pe
                    int bb = row / 25, pos = row - bb*25;
                    float freq = __powf(10000.0f, -(float)col / 128.0f);
                    float a = (float)pos * freq;
                    float pe = 0.7310585786300049f * ((col & 1) ? __cosf(a) : __sinf(a));
                    ((u16*)Cout)[(size_t)(bb*SEQ + 1 + pos)*256 + col] = f2bf(v + pe);
                } else if (OUTBF) {
                    ((u16*)Cout)[(size_t)row*N + col] = f2bf(v);
                } else {
                    ((float*)Cout)[(size_t)row*N + col] = v;
                }
            }
        }
    }
}

// ---------------------------------------------------------------------------
// LayerNorm over D=512, bf16 out; grid TOK, block 256
__global__ void ln_kernel(const float* __restrict__ x, const float* __restrict__ g,
                          const float* __restrict__ bta, u16* __restrict__ out) {
    int t = blockIdx.x;
    int tid = threadIdx.x;
    const float* xr = x + (size_t)t*DIM;
    float v0 = xr[tid], v1 = xr[tid+256];
    float s = v0 + v1, sq = v0*v0 + v1*v1;
    __shared__ float rs[4], rq[4];
    for (int off = 32; off; off >>= 1) { s += __shfl_down(s, off); sq += __shfl_down(sq, off); }
    int wid = tid >> 6, lane = tid & 63;
    if (lane == 0) { rs[wid] = s; rq[wid] = sq; }
    __syncthreads();
    __shared__ float mean_s, rstd_s;
    if (tid == 0) {
        float ts = rs[0]+rs[1]+rs[2]+rs[3], tq = rq[0]+rq[1]+rq[2]+rq[3];
        float m = ts / DIM;
        float var = tq / DIM - m*m;
        mean_s = m; rstd_s = rsqrtf(var + 1e-5f);
    }
    __syncthreads();
    float m = mean_s, r = rstd_s;
    out[(size_t)t*DIM + tid]       = f2bf((v0 - m)*r*g[tid]     + bta[tid]);
    out[(size_t)t*DIM + tid + 256] = f2bf((v1 - m)*r*g[tid+256] + bta[tid+256]);
}

// ---------------------------------------------------------------------------
// Fused attention, 2 blocks per batch (grid (2,NB), 256 threads = 4 waves).
// Block (half,b): heads h = half*4 .. half*4+3.
//  (a) wave w computes S_{half*4+w} = softmax_k(Q K^T / 8) -> s_lds [112][28]
//  (b) vw[k,r] = sum_d2 V[k,r*64+d2]*sw[d2]   (duplicated per half, cheap)
//  (c) e[row,r] = sum_k s*vw; comp = softmax_r(e)   (qv & score_b cancel)
//  (d) o = (s*comp) @ Vflat  via MFMA (rows 104 pad 112, K=208 pad 224)
// Pad rows only corrupt discarded C rows (MFMA A-row<->C-row is 1:1).
__global__ __launch_bounds__(256) void attn_fused_kernel(const u16* __restrict__ qkv,
                                                         const float* __restrict__ score_w,
                                                         u16* __restrict__ attn_o) {
    int half = blockIdx.x, b = blockIdx.y;
    __shared__ u16 Bt[64*224];        // V as [d2][kr], byte ^= (d2&7)<<4
    __shared__ float s_lds[112*28];   // [(w*26+q)][k], k 26..27 = 0; rows 104..111 pad
    __shared__ float vwl[208];        // [k*8+r]
    __shared__ float cmp_lds[112*8];  // [row][r]
    __shared__ float swl[64];
    int tid = threadIdx.x;
    int lane = tid & 63, w = tid >> 6;   // w 0..3

    if (tid < 64) swl[tid] = score_w[32 + tid];
    // V -> Bt (transpose to [d2][kr]); coalesced global bf16 reads (2 elems/thread)
    for (int k = 0; k < 26; ++k) {
        #pragma unroll
        for (int s = 0; s < 2; ++s) {
            int idx = s*256 + tid;
            int d2 = idx & 63, r = idx >> 6;
            u16 v = qkv[(size_t)(b*SEQ+k)*1536 + 1024 + idx];
            int bo = (d2*448 + (k*8+r)*2) ^ ((d2 & 7) << 4);
            *(u16*)((char*)Bt + bo) = v;
        }
    }
    // zero-pad kr 208..223 (1024 slots)
    #pragma unroll
    for (int s = 0; s < 4; ++s) {
        int idx = s*256 + tid;
        int d2 = idx & 63, kr = 208 + (idx >> 6);
        int bo = (d2*448 + kr*2) ^ ((d2 & 7) << 4);
        *(u16*)((char*)Bt + bo) = 0;
    }
    // zero s_lds pad cols + pad rows, cmp pad rows
    for (int row = tid; row < 112; row += 256) { s_lds[row*28 + 26] = 0.f; s_lds[row*28 + 27] = 0.f; }
    for (int idx = tid; idx < 8*28; idx += 256) s_lds[104*28 + idx] = 0.f;
    for (int idx = tid; idx < 8*8;  idx += 256) cmp_lds[104*8 + idx] = 0.f;

    // ---- (a) QK^T + softmax, wave w -> head half*4+w, local rows w*26+q ----
    {
        int h = half*4 + w;
        int col16 = lane & 15, ch = lane >> 4;
        short8_t qf[2][2], kf[2][2];
        #pragma unroll
        for (int mi = 0; mi < 2; ++mi) {
            int q = mi*16 + col16;
            #pragma unroll
            for (int kk = 0; kk < 2; ++kk) {
                if (q < 26)
                    qf[mi][kk] = *(const short8_t*)&qkv[(size_t)(b*SEQ+q)*1536 + h*64 + kk*32 + ch*8];
                else
                    qf[mi][kk] = (short8_t){0,0,0,0,0,0,0,0};
            }
        }
        #pragma unroll
        for (int ni = 0; ni < 2; ++ni) {
            int kq = ni*16 + col16;
            #pragma unroll
            for (int kk = 0; kk < 2; ++kk) {
                if (kq < 26)
                    kf[ni][kk] = *(const short8_t*)&qkv[(size_t)(b*SEQ+kq)*1536 + 512 + h*64 + kk*32 + ch*8];
                else
                    kf[ni][kk] = (short8_t){0,0,0,0,0,0,0,0};
            }
        }
        floatx4 sacc[2][2];
        #pragma unroll
        for (int mi = 0; mi < 2; ++mi)
            #pragma unroll
            for (int ni = 0; ni < 2; ++ni)
                sacc[mi][ni] = (floatx4){0.f,0.f,0.f,0.f};
        #pragma unroll
        for (int kk = 0; kk < 2; ++kk)
            #pragma unroll
            for (int mi = 0; mi < 2; ++mi)
                #pragma unroll
                for (int ni = 0; ni < 2; ++ni)
                    sacc[mi][ni] = __builtin_amdgcn_mfma_f32_16x16x32_bf16(
                        qf[mi][kk], kf[ni][kk], sacc[mi][ni], 0, 0, 0);
        #pragma unroll
        for (int mi = 0; mi < 2; ++mi) {
            #pragma unroll
            for (int r = 0; r < 4; ++r) {
                float s0 = sacc[mi][0][r] * 0.125f;
                float s1 = (col16 < 10) ? sacc[mi][1][r] * 0.125f : -1e30f;
                float mx = fmaxf(s0, s1);
                #pragma unroll
                for (int msk = 1; msk < 16; msk <<= 1) mx = fmaxf(mx, __shfl_xor(mx, msk));
                float e0 = __expf(s0 - mx);
                float e1 = (col16 < 10) ? __expf(s1 - mx) : 0.f;
                float den = e0 + e1;
                #pragma unroll
                for (int msk = 1; msk < 16; msk <<= 1) den += __shfl_xor(den, msk);
                float inv = 1.f / den;
                int q = mi*16 + ch*4 + r;
                if (q < 26) {
                    s_lds[(w*26+q)*28 + col16] = e0 * inv;
                    if (col16 < 10) s_lds[(w*26+q)*28 + 16 + col16] = e1 * inv;
                }
            }
        }
    }
    __syncthreads();

    // ---- (b) vw ----
    if (tid < 208) {
        float acc = 0.f;
        #pragma unroll
        for (int d2 = 0; d2 < 64; ++d2) {
            int bo = (d2*448 + tid*2) ^ ((d2 & 7) << 4);
            acc += bf2f(*(const u16*)((const char*)Bt + bo)) * swl[d2];
        }
        vwl[tid] = acc;
    }
    __syncthreads();

    // ---- (c) e + softmax over r (rows 0..103 local) ----
    if (tid < 104) {
        float srow[26];
        #pragma unroll
        for (int k = 0; k < 26; ++k) srow[k] = s_lds[tid*28 + k];
        float e[8];
        #pragma unroll
        for (int r = 0; r < 8; ++r) {
            float a = 0.f;
            #pragma unroll
            for (int k = 0; k < 26; ++k) a += srow[k] * vwl[k*8 + r];
            e[r] = a;
        }
        float m = e[0];
        #pragma unroll
        for (int r = 1; r < 8; ++r) m = fmaxf(m, e[r]);
        float den = 0.f;
        #pragma unroll
        for (int r = 0; r < 8; ++r) { e[r] = __expf(e[r]-m); den += e[r]; }
        float inv = 1.f/den;
        #pragma unroll
        for (int r = 0; r < 8; ++r) cmp_lds[tid*8+r] = e[r]*inv;
    }
    __syncthreads();

    // ---- (d) MFMA: C[112][64] = w2[112][224] @ Vflat[224][64]; wave w owns cols w*16.. ----
    int ntile0 = w*16;
    short8_t bfr[7];
    #pragma unroll
    for (int ks = 0; ks < 7; ++ks) {
        int col = ntile0 + (lane & 15);
        int krb = ks*32 + (lane >> 4)*8;
        int bo = (col*448 + krb*2) ^ ((col & 7) << 4);
        bfr[ks] = *(const short8_t*)((const char*)Bt + bo);
    }
    for (int mt = 0; mt < 7; ++mt) {
        int arow = mt*16 + (lane & 15);
        float c8[8];
        #pragma unroll
        for (int r = 0; r < 8; ++r) c8[r] = cmp_lds[arow*8 + r];
        floatx4 acc = (floatx4){0.f,0.f,0.f,0.f};
        #pragma unroll
        for (int ks = 0; ks < 7; ++ks) {
            int k = ks*4 + (lane >> 4);
            float sv = s_lds[arow*28 + k];
            short8_t af;
            #pragma unroll
            for (int j = 0; j < 8; ++j) af[j] = (short)f2bf(sv * c8[j]);
            acc = __builtin_amdgcn_mfma_f32_16x16x32_bf16(af, bfr[ks], acc, 0, 0, 0);
        }
        int colg = ntile0 + (lane & 15);
        #pragma unroll
        for (int rr = 0; rr < 4; ++rr) {
            int rowl = mt*16 + (lane >> 4)*4 + rr;
            if (rowl < 104) {
                int rowg = half*104 + rowl;
                int h = rowg / 26, q = rowg - h*26;
                attn_o[(size_t)(b*SEQ+q)*DIM + h*64 + colg] = f2bf(acc[rr]);
            }
        }
    }
}

// ---------------------------------------------------------------------------
// head: y = x[:,0,:]@out_w+out_b; log_softmax. grid B, block 256, d-parallel.
__global__ void head_kernel(const float* __restrict__ x, const float* __restrict__ out_w,
                            const float* __restrict__ out_b, float* __restrict__ y) {
    int b = blockIdx.x;
    int tid = threadIdx.x;
    const float* xr = x + (size_t)(b*SEQ)*DIM;
    float x0 = xr[tid], x1 = xr[tid+256];
    float part[10];
    #pragma unroll
    for (int c = 0; c < 10; ++c)
        part[c] = x0*out_w[tid*10 + c] + x1*out_w[(tid+256)*10 + c];
    #pragma unroll
    for (int off = 32; off; off >>= 1)
        #pragma unroll
        for (int c = 0; c < 10; ++c) part[c] += __shfl_down(part[c], off);
    __shared__ float red[4][10];
    __shared__ float yv[10];
    int wid = tid >> 6, lane = tid & 63;
    if (lane == 0)
        #pragma unroll
        for (int c = 0; c < 10; ++c) red[wid][c] = part[c];
    __syncthreads();
    if (tid < 10)
        yv[tid] = out_b[tid] + red[0][tid] + red[1][tid] + red[2][tid] + red[3][tid];
    __syncthreads();
    if (tid < 10) {
        float m = yv[0];
        #pragma unroll
        for (int i = 1; i < 10; ++i) m = fmaxf(m, yv[i]);
        float den = 0.0f;
        #pragma unroll
        for (int i = 0; i < 10; ++i) den += __expf(yv[i]-m);
        y[b*10 + tid] = yv[tid] - m - __logf(den);
    }
}

// ---------------------------------------------------------------------------
extern "C" void kernel_launch(void* const* d_in, const int* in_sizes, int n_in,
                              void* d_out, int out_size, void* d_ws, size_t ws_size,
                              hipStream_t stream) {
    const float* img      = (const float*)d_in[0];
    const float* qst      = (const float*)d_in[1];
    const float* conv_w   = (const float*)d_in[2];
    const float* conv_b   = (const float*)d_in[3];
    const float* qrep_w   = (const float*)d_in[4];
    const float* qrep_b   = (const float*)d_in[5];
    const float* cls_tok  = (const float*)d_in[6];
    const float* map_w    = (const float*)d_in[7];
    const float* map_b    = (const float*)d_in[8];
    const float* norm1_g  = (const float*)d_in[9];
    const float* norm1_b  = (const float*)d_in[10];
    const float* norm2_g  = (const float*)d_in[11];
    const float* norm2_b  = (const float*)d_in[12];
    const float* q_w      = (const float*)d_in[13];
    const float* q_b      = (const float*)d_in[14];
    const float* k_w      = (const float*)d_in[15];
    const float* k_b      = (const float*)d_in[16];
    const float* v_w      = (const float*)d_in[17];
    const float* v_b      = (const float*)d_in[18];
    // d_in[19] qv_w, d_in[20] qv_b: cancel in r-softmax — unused
    const float* score_w  = (const float*)d_in[21];
    // d_in[22] score_b: constant along softmax axis — unused
    const float* final_w  = (const float*)d_in[23];
    const float* final_b  = (const float*)d_in[24];
    const float* ffn1_w   = (const float*)d_in[25];
    const float* ffn1_b   = (const float*)d_in[26];
    const float* ffn2_w   = (const float*)d_in[27];
    const float* ffn2_b   = (const float*)d_in[28];
    const float* out_w    = (const float*)d_in[29];
    const float* out_b    = (const float*)d_in[30];

    float* ws = (float*)d_ws;
    size_t o = 0;
    float* x    = ws + o;       o += (size_t)TOK*DIM;
    u16* qkvT   = (u16*)(ws+o); o += (size_t)1536*512/2;
    u16* finT   = (u16*)(ws+o); o += (size_t)512*512/2;
    u16* f1T    = (u16*)(ws+o); o += (size_t)1024*512/2;
    u16* f2T    = (u16*)(ws+o); o += (size_t)512*1024/2;
    u16* mapT   = (u16*)(ws+o); o += (size_t)512*256/2;
    u16* cwT    = (u16*)(ws+o); o += (size_t)256*704/2;
    float* qkvb = ws + o;       o += 1536;
    float* r2   = ws + o;
    // phase-2 layout in r2
    u16*  h_bf    = (u16*)r2;                                  // TOK*512 bf16
    u16*  qkv_bf  = (u16*)(r2 + (size_t)TOK*DIM/2);            // TOK*1536 bf16
    u16*  attn_obf= (u16*)(r2 + (size_t)TOK*DIM/2 + (size_t)TOK*1536/2); // TOK*512 bf16
    u16*  ffbuf   = qkv_bf;                                    // alias (qkv dead in FFN)
    // phase-1 aliases r2
    u16*  Pbuf    = (u16*)r2;                                  // 6400*704 bf16
    u16*  emb_bf  = (u16*)(r2 + (size_t)6400*704/2);           // TOK*256 bf16
    float* quem   = r2 + (size_t)6400*704/2 + (size_t)TOK*256/2;

    // ---- weight prep + cls rows + question path: one dispatch ----
    prep_all<<<1313, 256, 0, stream>>>(q_w, k_w, v_w, final_w, ffn1_w, ffn2_w, map_w, conv_w,
                                       q_b, k_b, v_b, cls_tok, qst, qrep_w, qrep_b, map_b,
                                       qkvT, finT, f1T, f2T, mapT, cwT, qkvb, emb_bf, quem);

    // ---- phase 1: embedding ----
    im2col_kernel<<<6400, 256, 0, stream>>>(img, Pbuf);
    // conv patch-GEMM writes emb rows directly (+pe), bf16
    mfma_gemm<64,3,0,1><<<dim3(2,100), dim3(512), 0, stream>>>(
        Pbuf, cwT, conv_b, nullptr, emb_bf, 6400, 256, 704, 1.0f);
    mfma_gemm<64,2,0,0><<<dim3(4,104), dim3(512), 0, stream>>>(
        emb_bf, mapT, nullptr, quem, x, TOK, 512, 256, 1.0f);

    // ---- phase 2: 4 transformer iterations ----
    for (int it = 0; it < 4; ++it) {
        ln_kernel<<<TOK, 256, 0, stream>>>(x, norm1_g, norm1_b, h_bf);
        mfma_gemm<128,0,0,1><<<dim3(12,52), dim3(512), 0, stream>>>(
            h_bf, qkvT, qkvb, nullptr, qkv_bf, TOK, 1536, 512, 1.0f);
        attn_fused_kernel<<<dim3(2,NB), 256, 0, stream>>>(qkv_bf, score_w, attn_obf);
        mfma_gemm<64,1,0,0><<<dim3(4,104), dim3(512), 0, stream>>>(
            attn_obf, finT, final_b, x, x, TOK, 512, 512, 1.0f);
        ln_kernel<<<TOK, 256, 0, stream>>>(x, norm2_g, norm2_b, h_bf);
        mfma_gemm<128,0,1,1><<<dim3(8,52), dim3(512), 0, stream>>>(
            h_bf, f1T, ffn1_b, nullptr, ffbuf, TOK, 1024, 512, 1.0f);
        mfma_gemm<64,1,0,0><<<dim3(4,104), dim3(512), 0, stream>>>(
            ffbuf, f2T, ffn2_b, x, x, TOK, 512, 1024, 1.0f);
    }

    head_kernel<<<NB, 256, 0, stream>>>(x, out_w, out_b, (float*)d_out);
}

// Round 11
// 519.289 us; speedup vs baseline: 1.0925x; 1.0925x over previous
//
#include <hip/hip_runtime.h>
#include <math.h>

#define NB 256
#define SEQ 26
#define TOK (NB*SEQ)   // 6656
#define DIM 512

typedef unsigned short u16;
typedef __attribute__((ext_vector_type(8))) short short8_t;
typedef __attribute__((ext_vector_type(4))) float floatx4;

__device__ inline u16 f2bf(float f) {
    union { float f; unsigned u; } v; v.f = f;
    unsigned r = v.u + 0x7fffu + ((v.u >> 16) & 1u);
    return (u16)(r >> 16);
}
__device__ inline float bf2f(u16 u) {
    union { unsigned u; float f; } v; v.u = ((unsigned)u) << 16; return v.f;
}

__device__ __forceinline__ void gload_lds16(const u16* g, u16* l) {
    __builtin_amdgcn_global_load_lds((const __attribute__((address_space(1))) void*)g,
                                     (__attribute__((address_space(3))) void*)l, 16, 0, 0);
}

// ---------------------------------------------------------------------------
// One-shot prep: weight transposes (f32->bf16 [N][K]), conv_w pad-copy,
// cls rows, qkv bias concat, AND the per-batch question path (que_map).
// Grid 1313, block 256.
__global__ void prep_all(const float* __restrict__ q_w, const float* __restrict__ k_w,
                         const float* __restrict__ v_w, const float* __restrict__ final_w,
                         const float* __restrict__ ffn1_w, const float* __restrict__ ffn2_w,
                         const float* __restrict__ map_w, const float* __restrict__ conv_w,
                         const float* __restrict__ q_b, const float* __restrict__ k_b,
                         const float* __restrict__ v_b, const float* __restrict__ cls,
                         const float* __restrict__ qst, const float* __restrict__ qrep_w,
                         const float* __restrict__ qrep_b, const float* __restrict__ map_b,
                         u16* __restrict__ qkvT, u16* __restrict__ finT,
                         u16* __restrict__ f1T, u16* __restrict__ f2T,
                         u16* __restrict__ mapT, u16* __restrict__ cwT,
                         float* __restrict__ qkvb, u16* __restrict__ emb,
                         float* __restrict__ quem) {
    __shared__ float lds[64][65];
    __shared__ float que[256];
    int blk = blockIdx.x;
    int t = threadIdx.x;
    if (blk < 544) {
        const float* W; u16* Wt; int K, N, tbase;
        if (blk < 64)       { W = q_w;     Wt = qkvT;            K = 512;  N = 512;  tbase = 0;   }
        else if (blk < 128) { W = k_w;     Wt = qkvT + 512*512;  K = 512;  N = 512;  tbase = 64;  }
        else if (blk < 192) { W = v_w;     Wt = qkvT + 1024*512; K = 512;  N = 512;  tbase = 128; }
        else if (blk < 256) { W = final_w; Wt = finT;            K = 512;  N = 512;  tbase = 192; }
        else if (blk < 384) { W = ffn1_w;  Wt = f1T;             K = 512;  N = 1024; tbase = 256; }
        else if (blk < 512) { W = ffn2_w;  Wt = f2T;             K = 1024; N = 512;  tbase = 384; }
        else                { W = map_w;   Wt = mapT;            K = 256;  N = 512;  tbase = 512; }
        int tloc = blk - tbase;
        int ntn = N >> 6;
        int n0 = (tloc % ntn) * 64, k0 = (tloc / ntn) * 64;
        int j = t & 63, i0 = t >> 6;
        #pragma unroll
        for (int p = 0; p < 16; ++p) {
            int i = i0*16 + p;
            lds[i][j] = W[(size_t)(k0+i)*N + n0 + j];
        }
        __syncthreads();
        int i2 = t & 63, j0 = t >> 6;
        #pragma unroll
        for (int p = 0; p < 16; ++p) {
            int j2 = j0*16 + p;
            Wt[(size_t)(n0+j2)*K + k0 + i2] = f2bf(lds[i2][j2]);
        }
    } else if (blk < 800) {
        int oc = blk - 544;
        for (int jj = t; jj < 704; jj += 256)
            cwT[(size_t)oc*704 + jj] = (jj < 675) ? f2bf(conv_w[(size_t)oc*675 + jj]) : (u16)0;
    } else if (blk < 1056) {
        int b = blk - 800;  // cls row for batch b
        emb[(size_t)(b*SEQ)*256 + t] = f2bf(cls[t]);
    } else if (blk == 1056) {
        for (int jj = t; jj < 1536; jj += 256)
            qkvb[jj] = jj < 512 ? q_b[jj] : (jj < 1024 ? k_b[jj-512] : v_b[jj-1024]);
    } else {
        int b = blk - 1057;  // question path for batch b
        float acc = qrep_b[t];
        for (int j = 0; j < 18; ++j) acc += qst[b*18 + j] * qrep_w[j*256 + t];
        que[t] = acc;
        __syncthreads();
        for (int n = t; n < DIM; n += 256) {
            float a2 = map_b[n];
            for (int k = 0; k < 256; ++k) a2 += que[k] * map_w[(256 + k)*DIM + n];
            quem[b*DIM + n] = a2;
        }
    }
}

// ---------------------------------------------------------------------------
// im2col: P[(b*25+pos)][j] bf16, K padded to 704
__global__ void im2col_kernel(const float* __restrict__ img, u16* __restrict__ P) {
    int ri = blockIdx.x;               // 0..6399
    int b = ri / 25, pos = ri % 25, ph = pos/5, pw = pos%5;
    for (int j = threadIdx.x; j < 704; j += 256) {
        float v = 0.f;
        if (j < 675) {
            int c = j / 225, rem = j % 225, kh = rem/15, kw = rem%15;
            v = img[(size_t)((b*3+c)*75 + ph*15 + kh)*75 + pw*15 + kw];
        }
        P[(size_t)ri*704 + j] = f2bf(v);
    }
}

// ---------------------------------------------------------------------------
// bf16 MFMA GEMM: C[M,N] = op(A[M,K] @ B + bias)*alpha [+res],  B given as Bt[N,K].
// BM x 128 tile (BM=128 or 64), BK=64, 512 threads (8 waves, 2x4).
// Double-buffered LDS; global_load_lds width=16; linear LDS dest with
// PRE-SWIZZLED global source (ch' = ch ^ (row&7)); ds_read applies same XOR.
// RESMODE: 0 none, 1 +res[row*N+col], 2 +res[(row/26)*N+col],
//          3 conv->emb: out row b*26+1+pos (+pe), bf16.
template<int BM, int RESMODE, int RELU, int OUTBF>
__global__ __launch_bounds__(512) void mfma_gemm(const u16* __restrict__ A, const u16* __restrict__ Bt,
                          const float* __restrict__ bias, const float* __restrict__ res,
                          void* __restrict__ Cout, int M, int N, int K, float alpha) {
    constexpr int MI  = BM / 32;   // acc row-tiles per wave
    constexpr int ALD = BM / 64;   // A gloads per thread
    __shared__ __align__(16) u16 As[2][BM*64];
    __shared__ __align__(16) u16 Bs[2][128*64];
    const int tid = threadIdx.x;
    const int lane = tid & 63;
    const int w = tid >> 6;             // 0..7
    const int wr = (w >> 2) * (MI*16);
    const int wc = (w & 3) * 32;
    const int bm = blockIdx.y * BM, bn = blockIdx.x * 128;

    floatx4 acc[MI][2];
    #pragma unroll
    for (int mi = 0; mi < MI; ++mi)
        #pragma unroll
        for (int ni = 0; ni < 2; ++ni)
            acc[mi][ni] = (floatx4){0.f,0.f,0.f,0.f};

    // staging addresses (loop-invariant)
    const u16* aptr[ALD];
    int aidx[ALD];
    #pragma unroll
    for (int s = 0; s < ALD; ++s) {
        int idx = s*512 + tid;
        int row = idx >> 3, ch = (idx & 7) ^ (row & 7);
        aptr[s] = &A[(size_t)(bm+row)*K + ch*8];
        aidx[s] = idx;
    }
    const u16* bptr[2];
    int bidx[2];
    #pragma unroll
    for (int s = 0; s < 2; ++s) {
        int idx = s*512 + tid;
        int row = idx >> 3, ch = (idx & 7) ^ (row & 7);
        bptr[s] = &Bt[(size_t)(bn+row)*K + ch*8];
        bidx[s] = idx;
    }

    const int nt = K >> 6;
    // prologue: stage tile 0 into buf 0
    #pragma unroll
    for (int s = 0; s < ALD; ++s) gload_lds16(aptr[s], &As[0][aidx[s]*8]);
    #pragma unroll
    for (int s = 0; s < 2; ++s)   gload_lds16(bptr[s], &Bs[0][bidx[s]*8]);
    __syncthreads();

    for (int t = 0; t < nt; ++t) {
        const int cur = t & 1;
        if (t + 1 < nt) {   // prefetch next tile into other buffer (overlaps MFMA)
            int off = (t + 1) << 6;
            #pragma unroll
            for (int s = 0; s < ALD; ++s) gload_lds16(aptr[s] + off, &As[cur^1][aidx[s]*8]);
            #pragma unroll
            for (int s = 0; s < 2; ++s)   gload_lds16(bptr[s] + off, &Bs[cur^1][bidx[s]*8]);
        }
        #pragma unroll
        for (int kk = 0; kk < 2; ++kk) {
            int ch2 = kk*4 + (lane >> 4);
            short8_t af[MI], bf[2];
            #pragma unroll
            for (int mi = 0; mi < MI; ++mi) {
                int row = wr + mi*16 + (lane & 15);
                af[mi] = *(const short8_t*)&As[cur][row*64 + ((ch2 ^ (row & 7))*8)];
            }
            #pragma unroll
            for (int ni = 0; ni < 2; ++ni) {
                int rowb = wc + ni*16 + (lane & 15);
                bf[ni] = *(const short8_t*)&Bs[cur][rowb*64 + ((ch2 ^ (rowb & 7))*8)];
            }
            #pragma unroll
            for (int mi = 0; mi < MI; ++mi)
                #pragma unroll
                for (int ni = 0; ni < 2; ++ni)
                    acc[mi][ni] = __builtin_amdgcn_mfma_f32_16x16x32_bf16(
                        af[mi], bf[ni], acc[mi][ni], 0, 0, 0);
        }
        __syncthreads();   // drains prefetch vmcnt + all lgkm; next tile ready
    }

    #pragma unroll
    for (int mi = 0; mi < MI; ++mi) {
        #pragma unroll
        for (int ni = 0; ni < 2; ++ni) {
            int col = bn + wc + ni*16 + (lane & 15);
            float bv = bias ? bias[col] : 0.0f;
            #pragma unroll
            for (int r = 0; r < 4; ++r) {
                int row = bm + wr + mi*16 + (lane >> 4)*4 + r;
                float v = (acc[mi][ni][r] + bv) * alpha;
                if (RELU) v = fmaxf(v, 0.f);
                if (RESMODE == 1)      v += res[(size_t)row*N + col];
                else if (RESMODE == 2) v += res[(size_t)(row/SEQ)*N + col];
                if (RESMODE == 3) {
                    // conv output row = b*25+pos -> emb row b*26+1+pos, plus pe
                    int bb = row / 25, pos = row - bb*25;
                    float freq = __powf(10000.0f, -(float)col / 128.0f);
                    float a = (float)pos * freq;
                    float pe = 0.7310585786300049f * ((col & 1) ? __cosf(a) : __sinf(a));
                    ((u16*)Cout)[(size_t)(bb*SEQ + 1 + pos)*256 + col] = f2bf(v + pe);
                } else if (OUTBF) {
                    ((u16*)Cout)[(size_t)row*N + col] = f2bf(v);
                } else {
                    ((float*)Cout)[(size_t)row*N + col] = v;
                }
            }
        }
    }
}

// ---------------------------------------------------------------------------
// LayerNorm over D=512, bf16 out. Wave-per-row: 4 rows/block, grid TOK/4.
// Each lane holds 8 contiguous f32 (2x float4); 64-lane shfl_xor butterfly for
// sum/sumsq; no LDS, no barriers; 16B bf16x8 store.
__global__ void ln_kernel(const float* __restrict__ x, const float* __restrict__ g,
                          const float* __restrict__ bta, u16* __restrict__ out) {
    int row = blockIdx.x * 4 + (threadIdx.x >> 6);
    int lane = threadIdx.x & 63;
    const float* xr = x + (size_t)row*DIM + lane*8;
    floatx4 a = *(const floatx4*)xr;
    floatx4 b = *(const floatx4*)(xr + 4);
    float s  = a[0]+a[1]+a[2]+a[3] + b[0]+b[1]+b[2]+b[3];
    float sq = a[0]*a[0]+a[1]*a[1]+a[2]*a[2]+a[3]*a[3]
             + b[0]*b[0]+b[1]*b[1]+b[2]*b[2]+b[3]*b[3];
    #pragma unroll
    for (int off = 32; off; off >>= 1) {
        s  += __shfl_xor(s,  off);
        sq += __shfl_xor(sq, off);
    }
    float m = s * (1.0f/DIM);
    float r = rsqrtf(sq * (1.0f/DIM) - m*m + 1e-5f);
    floatx4 g0 = *(const floatx4*)(g + lane*8);
    floatx4 g1 = *(const floatx4*)(g + lane*8 + 4);
    floatx4 b0 = *(const floatx4*)(bta + lane*8);
    floatx4 b1 = *(const floatx4*)(bta + lane*8 + 4);
    short8_t o;
    o[0] = (short)f2bf((a[0]-m)*r*g0[0] + b0[0]);
    o[1] = (short)f2bf((a[1]-m)*r*g0[1] + b0[1]);
    o[2] = (short)f2bf((a[2]-m)*r*g0[2] + b0[2]);
    o[3] = (short)f2bf((a[3]-m)*r*g0[3] + b0[3]);
    o[4] = (short)f2bf((b[0]-m)*r*g1[0] + b1[0]);
    o[5] = (short)f2bf((b[1]-m)*r*g1[1] + b1[1]);
    o[6] = (short)f2bf((b[2]-m)*r*g1[2] + b1[2]);
    o[7] = (short)f2bf((b[3]-m)*r*g1[3] + b1[3]);
    *(short8_t*)&out[(size_t)row*DIM + lane*8] = o;
}

// ---------------------------------------------------------------------------
// Fully fused attention per batch b (512 threads = 8 waves):
//  (a) wave h computes S_h = softmax_k(Q_h K_h^T / 8) via MFMA -> s_lds [208][28]
//  (b) vw[k,r] = sum_d2 V[k,r*64+d2]*sw[d2]   (416 threads, shfl-pair reduce)
//  (c) e[hq,r] = sum_k s*vw; comp = softmax_r(e)   (qv & score_b cancel)
//  (d) o[(h,q),d2] = sum_kr (s*comp) @ Vflat  via MFMA (K=208 pad 224)
__global__ __launch_bounds__(512) void attn_fused_kernel(const u16* __restrict__ qkv,
                                                         const float* __restrict__ score_w,
                                                         u16* __restrict__ attn_o) {
    int b = blockIdx.x;
    __shared__ u16 Bt[64*224];        // V as [d2][kr], byte ^= (d2&7)<<4
    __shared__ float s_lds[208*28];   // [(h*26+q)][k], k 26..27 = 0
    __shared__ float vwl[208];        // [k*8+r]
    __shared__ float cmp_lds[208*8];  // [(h,q)][r]
    __shared__ float swl[64];
    int tid = threadIdx.x;
    int lane = tid & 63, w = tid >> 6;

    if (tid < 64) swl[tid] = score_w[32 + tid];
    // V -> Bt (transpose to [d2][kr]); coalesced global bf16 reads
    for (int k = 0; k < 26; ++k) {
        int d2 = tid & 63, r = tid >> 6;
        u16 v = qkv[(size_t)(b*SEQ+k)*1536 + 1024 + tid];
        int bo = (d2*448 + (k*8+r)*2) ^ ((d2 & 7) << 4);
        *(u16*)((char*)Bt + bo) = v;
    }
    {   // zero-pad kr 208..223
        int d2 = tid & 63, kr = 208 + (tid >> 6);
        int bo1 = (d2*448 + kr*2)     ^ ((d2 & 7) << 4);
        int bo2 = (d2*448 + (kr+8)*2) ^ ((d2 & 7) << 4);
        *(u16*)((char*)Bt + bo1) = 0;
        *(u16*)((char*)Bt + bo2) = 0;
    }
    // zero-pad s_lds cols 26,27
    for (int row = tid; row < 208; row += 512) {
        s_lds[row*28 + 26] = 0.f; s_lds[row*28 + 27] = 0.f;
    }

    // ---- (a) QK^T + softmax, wave w handles head h=w ----
    {
        int h = w;
        int col16 = lane & 15, ch = lane >> 4;
        short8_t qf[2][2], kf[2][2];
        #pragma unroll
        for (int mi = 0; mi < 2; ++mi) {
            int q = mi*16 + col16;
            #pragma unroll
            for (int kk = 0; kk < 2; ++kk) {
                if (q < 26)
                    qf[mi][kk] = *(const short8_t*)&qkv[(size_t)(b*SEQ+q)*1536 + h*64 + kk*32 + ch*8];
                else
                    qf[mi][kk] = (short8_t){0,0,0,0,0,0,0,0};
            }
        }
        #pragma unroll
        for (int ni = 0; ni < 2; ++ni) {
            int kq = ni*16 + col16;
            #pragma unroll
            for (int kk = 0; kk < 2; ++kk) {
                if (kq < 26)
                    kf[ni][kk] = *(const short8_t*)&qkv[(size_t)(b*SEQ+kq)*1536 + 512 + h*64 + kk*32 + ch*8];
                else
                    kf[ni][kk] = (short8_t){0,0,0,0,0,0,0,0};
            }
        }
        floatx4 sacc[2][2];
        #pragma unroll
        for (int mi = 0; mi < 2; ++mi)
            #pragma unroll
            for (int ni = 0; ni < 2; ++ni)
                sacc[mi][ni] = (floatx4){0.f,0.f,0.f,0.f};
        #pragma unroll
        for (int kk = 0; kk < 2; ++kk)
            #pragma unroll
            for (int mi = 0; mi < 2; ++mi)
                #pragma unroll
                for (int ni = 0; ni < 2; ++ni)
                    sacc[mi][ni] = __builtin_amdgcn_mfma_f32_16x16x32_bf16(
                        qf[mi][kk], kf[ni][kk], sacc[mi][ni], 0, 0, 0);
        #pragma unroll
        for (int mi = 0; mi < 2; ++mi) {
            #pragma unroll
            for (int r = 0; r < 4; ++r) {
                float s0 = sacc[mi][0][r] * 0.125f;
                float s1 = (col16 < 10) ? sacc[mi][1][r] * 0.125f : -1e30f;
                float mx = fmaxf(s0, s1);
                #pragma unroll
                for (int msk = 1; msk < 16; msk <<= 1) mx = fmaxf(mx, __shfl_xor(mx, msk));
                float e0 = __expf(s0 - mx);
                float e1 = (col16 < 10) ? __expf(s1 - mx) : 0.f;
                float den = e0 + e1;
                #pragma unroll
                for (int msk = 1; msk < 16; msk <<= 1) den += __shfl_xor(den, msk);
                float inv = 1.f / den;
                int q = mi*16 + ch*4 + r;
                if (q < 26) {
                    s_lds[(h*26+q)*28 + col16] = e0 * inv;
                    if (col16 < 10) s_lds[(h*26+q)*28 + 16 + col16] = e1 * inv;
                }
            }
        }
    }
    __syncthreads();

    // ---- (b) vw: 416 threads, each sums half the d2 range; pair-reduce ----
    if (tid < 416) {
        int kr = tid >> 1, h0 = (tid & 1) * 32;
        float acc = 0.f;
        #pragma unroll
        for (int dd = 0; dd < 32; ++dd) {
            int d2 = h0 + dd;
            int bo = (d2*448 + kr*2) ^ ((d2 & 7) << 4);
            acc += bf2f(*(const u16*)((const char*)Bt + bo)) * swl[d2];
        }
        acc += __shfl_xor(acc, 1);
        if ((tid & 1) == 0) vwl[kr] = acc;
    }
    __syncthreads();

    // ---- (c) e + softmax over r ----
    if (tid < 208) {
        float srow[26];
        #pragma unroll
        for (int k = 0; k < 26; ++k) srow[k] = s_lds[tid*28 + k];
        float e[8];
        #pragma unroll
        for (int r = 0; r < 8; ++r) {
            float a = 0.f;
            #pragma unroll
            for (int k = 0; k < 26; ++k) a += srow[k] * vwl[k*8 + r];
            e[r] = a;
        }
        float m = e[0];
        #pragma unroll
        for (int r = 1; r < 8; ++r) m = fmaxf(m, e[r]);
        float den = 0.f;
        #pragma unroll
        for (int r = 0; r < 8; ++r) { e[r] = __expf(e[r]-m); den += e[r]; }
        float inv = 1.f/den;
        #pragma unroll
        for (int r = 0; r < 8; ++r) cmp_lds[tid*8+r] = e[r]*inv;
    }
    __syncthreads();

    // ---- (d) MFMA: C[208][64] = w2[208][224] @ Vflat[224][64] ----
    int mh = w >> 2, nt = w & 3;
    int ntile0 = nt*16;
    short8_t bfr[7];
    #pragma unroll
    for (int ks = 0; ks < 7; ++ks) {
        int col = ntile0 + (lane & 15);
        int krb = ks*32 + (lane >> 4)*8;
        int bo = (col*448 + krb*2) ^ ((col & 7) << 4);
        bfr[ks] = *(const short8_t*)((const char*)Bt + bo);
    }
    int mt0 = mh ? 7 : 0, mt1 = mh ? 13 : 7;
    for (int mt = mt0; mt < mt1; ++mt) {
        int arow = mt*16 + (lane & 15);
        float c8[8];
        #pragma unroll
        for (int r = 0; r < 8; ++r) c8[r] = cmp_lds[arow*8 + r];
        floatx4 acc = (floatx4){0.f,0.f,0.f,0.f};
        #pragma unroll
        for (int ks = 0; ks < 7; ++ks) {
            int k = ks*4 + (lane >> 4);
            float sv = s_lds[arow*28 + k];
            short8_t af;
            #pragma unroll
            for (int j = 0; j < 8; ++j) af[j] = (short)f2bf(sv * c8[j]);
            acc = __builtin_amdgcn_mfma_f32_16x16x32_bf16(af, bfr[ks], acc, 0, 0, 0);
        }
        int colg = ntile0 + (lane & 15);
        #pragma unroll
        for (int rr = 0; rr < 4; ++rr) {
            int rowg = mt*16 + (lane >> 4)*4 + rr;
            int h = rowg / 26, q = rowg - h*26;
            attn_o[(size_t)(b*SEQ+q)*DIM + h*64 + colg] = f2bf(acc[rr]);
        }
    }
}

// ---------------------------------------------------------------------------
// head: y = x[:,0,:]@out_w+out_b; log_softmax. grid B, block 256, d-parallel.
__global__ void head_kernel(const float* __restrict__ x, const float* __restrict__ out_w,
                            const float* __restrict__ out_b, float* __restrict__ y) {
    int b = blockIdx.x;
    int tid = threadIdx.x;
    const float* xr = x + (size_t)(b*SEQ)*DIM;
    float x0 = xr[tid], x1 = xr[tid+256];
    float part[10];
    #pragma unroll
    for (int c = 0; c < 10; ++c)
        part[c] = x0*out_w[tid*10 + c] + x1*out_w[(tid+256)*10 + c];
    #pragma unroll
    for (int off = 32; off; off >>= 1)
        #pragma unroll
        for (int c = 0; c < 10; ++c) part[c] += __shfl_down(part[c], off);
    __shared__ float red[4][10];
    __shared__ float yv[10];
    int wid = tid >> 6, lane = tid & 63;
    if (lane == 0)
        #pragma unroll
        for (int c = 0; c < 10; ++c) red[wid][c] = part[c];
    __syncthreads();
    if (tid < 10)
        yv[tid] = out_b[tid] + red[0][tid] + red[1][tid] + red[2][tid] + red[3][tid];
    __syncthreads();
    if (tid < 10) {
        float m = yv[0];
        #pragma unroll
        for (int i = 1; i < 10; ++i) m = fmaxf(m, yv[i]);
        float den = 0.0f;
        #pragma unroll
        for (int i = 0; i < 10; ++i) den += __expf(yv[i]-m);
        y[b*10 + tid] = yv[tid] - m - __logf(den);
    }
}

// ---------------------------------------------------------------------------
extern "C" void kernel_launch(void* const* d_in, const int* in_sizes, int n_in,
                              void* d_out, int out_size, void* d_ws, size_t ws_size,
                              hipStream_t stream) {
    const float* img      = (const float*)d_in[0];
    const float* qst      = (const float*)d_in[1];
    const float* conv_w   = (const float*)d_in[2];
    const float* conv_b   = (const float*)d_in[3];
    const float* qrep_w   = (const float*)d_in[4];
    const float* qrep_b   = (const float*)d_in[5];
    const float* cls_tok  = (const float*)d_in[6];
    const float* map_w    = (const float*)d_in[7];
    const float* map_b    = (const float*)d_in[8];
    const float* norm1_g  = (const float*)d_in[9];
    const float* norm1_b  = (const float*)d_in[10];
    const float* norm2_g  = (const float*)d_in[11];
    const float* norm2_b  = (const float*)d_in[12];
    const float* q_w      = (const float*)d_in[13];
    const float* q_b      = (const float*)d_in[14];
    const float* k_w      = (const float*)d_in[15];
    const float* k_b      = (const float*)d_in[16];
    const float* v_w      = (const float*)d_in[17];
    const float* v_b      = (const float*)d_in[18];
    // d_in[19] qv_w, d_in[20] qv_b: cancel in r-softmax — unused
    const float* score_w  = (const float*)d_in[21];
    // d_in[22] score_b: constant along softmax axis — unused
    const float* final_w  = (const float*)d_in[23];
    const float* final_b  = (const float*)d_in[24];
    const float* ffn1_w   = (const float*)d_in[25];
    const float* ffn1_b   = (const float*)d_in[26];
    const float* ffn2_w   = (const float*)d_in[27];
    const float* ffn2_b   = (const float*)d_in[28];
    const float* out_w    = (const float*)d_in[29];
    const float* out_b    = (const float*)d_in[30];

    float* ws = (float*)d_ws;
    size_t o = 0;
    float* x    = ws + o;       o += (size_t)TOK*DIM;
    u16* qkvT   = (u16*)(ws+o); o += (size_t)1536*512/2;
    u16* finT   = (u16*)(ws+o); o += (size_t)512*512/2;
    u16* f1T    = (u16*)(ws+o); o += (size_t)1024*512/2;
    u16* f2T    = (u16*)(ws+o); o += (size_t)512*1024/2;
    u16* mapT   = (u16*)(ws+o); o += (size_t)512*256/2;
    u16* cwT    = (u16*)(ws+o); o += (size_t)256*704/2;
    float* qkvb = ws + o;       o += 1536;
    float* r2   = ws + o;
    // phase-2 layout in r2
    u16*  h_bf    = (u16*)r2;                                  // TOK*512 bf16
    u16*  qkv_bf  = (u16*)(r2 + (size_t)TOK*DIM/2);            // TOK*1536 bf16
    u16*  attn_obf= (u16*)(r2 + (size_t)TOK*DIM/2 + (size_t)TOK*1536/2); // TOK*512 bf16
    u16*  ffbuf   = qkv_bf;                                    // alias (qkv dead in FFN)
    // phase-1 aliases r2
    u16*  Pbuf    = (u16*)r2;                                  // 6400*704 bf16
    u16*  emb_bf  = (u16*)(r2 + (size_t)6400*704/2);           // TOK*256 bf16
    float* quem   = r2 + (size_t)6400*704/2 + (size_t)TOK*256/2;

    // ---- weight prep + cls rows + question path: one dispatch ----
    prep_all<<<1313, 256, 0, stream>>>(q_w, k_w, v_w, final_w, ffn1_w, ffn2_w, map_w, conv_w,
                                       q_b, k_b, v_b, cls_tok, qst, qrep_w, qrep_b, map_b,
                                       qkvT, finT, f1T, f2T, mapT, cwT, qkvb, emb_bf, quem);

    // ---- phase 1: embedding ----
    im2col_kernel<<<6400, 256, 0, stream>>>(img, Pbuf);
    // conv patch-GEMM writes emb rows directly (+pe), bf16
    mfma_gemm<64,3,0,1><<<dim3(2,100), dim3(512), 0, stream>>>(
        Pbuf, cwT, conv_b, nullptr, emb_bf, 6400, 256, 704, 1.0f);
    mfma_gemm<64,2,0,0><<<dim3(4,104), dim3(512), 0, stream>>>(
        emb_bf, mapT, nullptr, quem, x, TOK, 512, 256, 1.0f);

    // ---- phase 2: 4 transformer iterations ----
    for (int it = 0; it < 4; ++it) {
        ln_kernel<<<TOK/4, 256, 0, stream>>>(x, norm1_g, norm1_b, h_bf);
        mfma_gemm<128,0,0,1><<<dim3(12,52), dim3(512), 0, stream>>>(
            h_bf, qkvT, qkvb, nullptr, qkv_bf, TOK, 1536, 512, 1.0f);
        attn_fused_kernel<<<NB, 512, 0, stream>>>(qkv_bf, score_w, attn_obf);
        mfma_gemm<64,1,0,0><<<dim3(4,104), dim3(512), 0, stream>>>(
            attn_obf, finT, final_b, x, x, TOK, 512, 512, 1.0f);
        ln_kernel<<<TOK/4, 256, 0, stream>>>(x, norm2_g, norm2_b, h_bf);
        mfma_gemm<128,0,1,1><<<dim3(8,52), dim3(512), 0, stream>>>(
            h_bf, f1T, ffn1_b, nullptr, ffbuf, TOK, 1024, 512, 1.0f);
        mfma_gemm<64,1,0,0><<<dim3(4,104), dim3(512), 0, stream>>>(
            ffbuf, f2T, ffn2_b, x, x, TOK, 512, 1024, 1.0f);
    }

    head_kernel<<<NB, 256, 0, stream>>>(x, out_w, out_b, (float*)d_out);
}

// Round 12
// 510.209 us; speedup vs baseline: 1.1120x; 1.0178x over previous
//
#include <hip/hip_runtime.h>
#include <math.h>

#define NB 256
#define SEQ 26
#define TOK (NB*SEQ)   // 6656
#define DIM 512

typedef unsigned short u16;
typedef __attribute__((ext_vector_type(8))) short short8_t;
typedef __attribute__((ext_vector_type(4))) float floatx4;

__device__ inline u16 f2bf(float f) {
    union { float f; unsigned u; } v; v.f = f;
    unsigned r = v.u + 0x7fffu + ((v.u >> 16) & 1u);
    return (u16)(r >> 16);
}
__device__ inline float bf2f(u16 u) {
    union { unsigned u; float f; } v; v.u = ((unsigned)u) << 16; return v.f;
}

__device__ __forceinline__ void gload_lds16(const u16* g, u16* l) {
    __builtin_amdgcn_global_load_lds((const __attribute__((address_space(1))) void*)g,
                                     (__attribute__((address_space(3))) void*)l, 16, 0, 0);
}

// ---------------------------------------------------------------------------
// One-shot prep: weight transposes (f32->bf16 [N][K]), conv_w pad-copy,
// cls rows, qkv bias concat, AND the per-batch question path (que_map).
// Grid 1313, block 256.
__global__ void prep_all(const float* __restrict__ q_w, const float* __restrict__ k_w,
                         const float* __restrict__ v_w, const float* __restrict__ final_w,
                         const float* __restrict__ ffn1_w, const float* __restrict__ ffn2_w,
                         const float* __restrict__ map_w, const float* __restrict__ conv_w,
                         const float* __restrict__ q_b, const float* __restrict__ k_b,
                         const float* __restrict__ v_b, const float* __restrict__ cls,
                         const float* __restrict__ qst, const float* __restrict__ qrep_w,
                         const float* __restrict__ qrep_b, const float* __restrict__ map_b,
                         u16* __restrict__ qkvT, u16* __restrict__ finT,
                         u16* __restrict__ f1T, u16* __restrict__ f2T,
                         u16* __restrict__ mapT, u16* __restrict__ cwT,
                         float* __restrict__ qkvb, u16* __restrict__ emb,
                         float* __restrict__ quem) {
    __shared__ float lds[64][65];
    __shared__ float que[256];
    int blk = blockIdx.x;
    int t = threadIdx.x;
    if (blk < 544) {
        const float* W; u16* Wt; int K, N, tbase;
        if (blk < 64)       { W = q_w;     Wt = qkvT;            K = 512;  N = 512;  tbase = 0;   }
        else if (blk < 128) { W = k_w;     Wt = qkvT + 512*512;  K = 512;  N = 512;  tbase = 64;  }
        else if (blk < 192) { W = v_w;     Wt = qkvT + 1024*512; K = 512;  N = 512;  tbase = 128; }
        else if (blk < 256) { W = final_w; Wt = finT;            K = 512;  N = 512;  tbase = 192; }
        else if (blk < 384) { W = ffn1_w;  Wt = f1T;             K = 512;  N = 1024; tbase = 256; }
        else if (blk < 512) { W = ffn2_w;  Wt = f2T;             K = 1024; N = 512;  tbase = 384; }
        else                { W = map_w;   Wt = mapT;            K = 256;  N = 512;  tbase = 512; }
        int tloc = blk - tbase;
        int ntn = N >> 6;
        int n0 = (tloc % ntn) * 64, k0 = (tloc / ntn) * 64;
        int j = t & 63, i0 = t >> 6;
        #pragma unroll
        for (int p = 0; p < 16; ++p) {
            int i = i0*16 + p;
            lds[i][j] = W[(size_t)(k0+i)*N + n0 + j];
        }
        __syncthreads();
        int i2 = t & 63, j0 = t >> 6;
        #pragma unroll
        for (int p = 0; p < 16; ++p) {
            int j2 = j0*16 + p;
            Wt[(size_t)(n0+j2)*K + k0 + i2] = f2bf(lds[i2][j2]);
        }
    } else if (blk < 800) {
        int oc = blk - 544;
        for (int jj = t; jj < 704; jj += 256)
            cwT[(size_t)oc*704 + jj] = (jj < 675) ? f2bf(conv_w[(size_t)oc*675 + jj]) : (u16)0;
    } else if (blk < 1056) {
        int b = blk - 800;  // cls row for batch b
        emb[(size_t)(b*SEQ)*256 + t] = f2bf(cls[t]);
    } else if (blk == 1056) {
        for (int jj = t; jj < 1536; jj += 256)
            qkvb[jj] = jj < 512 ? q_b[jj] : (jj < 1024 ? k_b[jj-512] : v_b[jj-1024]);
    } else {
        int b = blk - 1057;  // question path for batch b
        float acc = qrep_b[t];
        for (int j = 0; j < 18; ++j) acc += qst[b*18 + j] * qrep_w[j*256 + t];
        que[t] = acc;
        __syncthreads();
        for (int n = t; n < DIM; n += 256) {
            float a2 = map_b[n];
            for (int k = 0; k < 256; ++k) a2 += que[k] * map_w[(256 + k)*DIM + n];
            quem[b*DIM + n] = a2;
        }
    }
}

// ---------------------------------------------------------------------------
// im2col: P[(b*25+pos)][j] bf16, K padded to 704
__global__ void im2col_kernel(const float* __restrict__ img, u16* __restrict__ P) {
    int ri = blockIdx.x;               // 0..6399
    int b = ri / 25, pos = ri % 25, ph = pos/5, pw = pos%5;
    for (int j = threadIdx.x; j < 704; j += 256) {
        float v = 0.f;
        if (j < 675) {
            int c = j / 225, rem = j % 225, kh = rem/15, kw = rem%15;
            v = img[(size_t)((b*3+c)*75 + ph*15 + kh)*75 + pw*15 + kw];
        }
        P[(size_t)ri*704 + j] = f2bf(v);
    }
}

// ---------------------------------------------------------------------------
// bf16 MFMA GEMM: C[M,N] = op(A[M,K] @ B + bias)*alpha [+res],  B given as Bt[N,K].
// BM x 128 tile (BM=128 or 64), BK=64, 512 threads (8 waves, 2x4).
// Double-buffered LDS; global_load_lds width=16; linear LDS dest with
// PRE-SWIZZLED global source (ch' = ch ^ (row&7)); ds_read applies same XOR.
// RESMODE: 0 none, 1 +bf16 res[row*N+col], 2 +f32 res[(row/26)*N+col],
//          3 conv->emb: out row b*26+1+pos (+pe), bf16.
template<int BM, int RESMODE, int RELU, int OUTBF>
__global__ __launch_bounds__(512) void mfma_gemm(const u16* __restrict__ A, const u16* __restrict__ Bt,
                          const float* __restrict__ bias, const void* __restrict__ res,
                          void* __restrict__ Cout, int M, int N, int K, float alpha) {
    constexpr int MI  = BM / 32;   // acc row-tiles per wave
    constexpr int ALD = BM / 64;   // A gloads per thread
    __shared__ __align__(16) u16 As[2][BM*64];
    __shared__ __align__(16) u16 Bs[2][128*64];
    const int tid = threadIdx.x;
    const int lane = tid & 63;
    const int w = tid >> 6;             // 0..7
    const int wr = (w >> 2) * (MI*16);
    const int wc = (w & 3) * 32;
    const int bm = blockIdx.y * BM, bn = blockIdx.x * 128;

    floatx4 acc[MI][2];
    #pragma unroll
    for (int mi = 0; mi < MI; ++mi)
        #pragma unroll
        for (int ni = 0; ni < 2; ++ni)
            acc[mi][ni] = (floatx4){0.f,0.f,0.f,0.f};

    // staging addresses (loop-invariant)
    const u16* aptr[ALD];
    int aidx[ALD];
    #pragma unroll
    for (int s = 0; s < ALD; ++s) {
        int idx = s*512 + tid;
        int row = idx >> 3, ch = (idx & 7) ^ (row & 7);
        aptr[s] = &A[(size_t)(bm+row)*K + ch*8];
        aidx[s] = idx;
    }
    const u16* bptr[2];
    int bidx[2];
    #pragma unroll
    for (int s = 0; s < 2; ++s) {
        int idx = s*512 + tid;
        int row = idx >> 3, ch = (idx & 7) ^ (row & 7);
        bptr[s] = &Bt[(size_t)(bn+row)*K + ch*8];
        bidx[s] = idx;
    }

    const int nt = K >> 6;
    // prologue: stage tile 0 into buf 0
    #pragma unroll
    for (int s = 0; s < ALD; ++s) gload_lds16(aptr[s], &As[0][aidx[s]*8]);
    #pragma unroll
    for (int s = 0; s < 2; ++s)   gload_lds16(bptr[s], &Bs[0][bidx[s]*8]);
    __syncthreads();

    for (int t = 0; t < nt; ++t) {
        const int cur = t & 1;
        if (t + 1 < nt) {   // prefetch next tile into other buffer (overlaps MFMA)
            int off = (t + 1) << 6;
            #pragma unroll
            for (int s = 0; s < ALD; ++s) gload_lds16(aptr[s] + off, &As[cur^1][aidx[s]*8]);
            #pragma unroll
            for (int s = 0; s < 2; ++s)   gload_lds16(bptr[s] + off, &Bs[cur^1][bidx[s]*8]);
        }
        #pragma unroll
        for (int kk = 0; kk < 2; ++kk) {
            int ch2 = kk*4 + (lane >> 4);
            short8_t af[MI], bf[2];
            #pragma unroll
            for (int mi = 0; mi < MI; ++mi) {
                int row = wr + mi*16 + (lane & 15);
                af[mi] = *(const short8_t*)&As[cur][row*64 + ((ch2 ^ (row & 7))*8)];
            }
            #pragma unroll
            for (int ni = 0; ni < 2; ++ni) {
                int rowb = wc + ni*16 + (lane & 15);
                bf[ni] = *(const short8_t*)&Bs[cur][rowb*64 + ((ch2 ^ (rowb & 7))*8)];
            }
            #pragma unroll
            for (int mi = 0; mi < MI; ++mi)
                #pragma unroll
                for (int ni = 0; ni < 2; ++ni)
                    acc[mi][ni] = __builtin_amdgcn_mfma_f32_16x16x32_bf16(
                        af[mi], bf[ni], acc[mi][ni], 0, 0, 0);
        }
        __syncthreads();   // drains prefetch vmcnt + all lgkm; next tile ready
    }

    #pragma unroll
    for (int mi = 0; mi < MI; ++mi) {
        #pragma unroll
        for (int ni = 0; ni < 2; ++ni) {
            int col = bn + wc + ni*16 + (lane & 15);
            float bv = bias ? bias[col] : 0.0f;
            #pragma unroll
            for (int r = 0; r < 4; ++r) {
                int row = bm + wr + mi*16 + (lane >> 4)*4 + r;
                float v = (acc[mi][ni][r] + bv) * alpha;
                if (RELU) v = fmaxf(v, 0.f);
                if (RESMODE == 1)      v += bf2f(((const u16*)res)[(size_t)row*N + col]);
                else if (RESMODE == 2) v += ((const float*)res)[(size_t)(row/SEQ)*N + col];
                if (RESMODE == 3) {
                    // conv output row = b*25+pos -> emb row b*26+1+pos, plus pe
                    int bb = row / 25, pos = row - bb*25;
                    float freq = __powf(10000.0f, -(float)col / 128.0f);
                    float a = (float)pos * freq;
                    float pe = 0.7310585786300049f * ((col & 1) ? __cosf(a) : __sinf(a));
                    ((u16*)Cout)[(size_t)(bb*SEQ + 1 + pos)*256 + col] = f2bf(v + pe);
                } else if (OUTBF) {
                    ((u16*)Cout)[(size_t)row*N + col] = f2bf(v);
                } else {
                    ((float*)Cout)[(size_t)row*N + col] = v;
                }
            }
        }
    }
}

// ---------------------------------------------------------------------------
// LayerNorm over D=512, bf16 in (residual stream) -> bf16 out.
// Wave-per-row: 4 rows/block, grid TOK/4. Each lane holds 8 contiguous bf16
// (one 16B load); 64-lane shfl_xor butterfly; no LDS, no barriers; 16B store.
__global__ void ln_kernel(const u16* __restrict__ x, const float* __restrict__ g,
                          const float* __restrict__ bta, u16* __restrict__ out) {
    int row = blockIdx.x * 4 + (threadIdx.x >> 6);
    int lane = threadIdx.x & 63;
    short8_t xin = *(const short8_t*)&x[(size_t)row*DIM + lane*8];
    float xv[8];
    #pragma unroll
    for (int j = 0; j < 8; ++j) xv[j] = bf2f((u16)xin[j]);
    float s = 0.f, sq = 0.f;
    #pragma unroll
    for (int j = 0; j < 8; ++j) { s += xv[j]; sq += xv[j]*xv[j]; }
    #pragma unroll
    for (int off = 32; off; off >>= 1) {
        s  += __shfl_xor(s,  off);
        sq += __shfl_xor(sq, off);
    }
    float m = s * (1.0f/DIM);
    float r = rsqrtf(sq * (1.0f/DIM) - m*m + 1e-5f);
    floatx4 g0 = *(const floatx4*)(g + lane*8);
    floatx4 g1 = *(const floatx4*)(g + lane*8 + 4);
    floatx4 b0 = *(const floatx4*)(bta + lane*8);
    floatx4 b1 = *(const floatx4*)(bta + lane*8 + 4);
    short8_t o;
    o[0] = (short)f2bf((xv[0]-m)*r*g0[0] + b0[0]);
    o[1] = (short)f2bf((xv[1]-m)*r*g0[1] + b0[1]);
    o[2] = (short)f2bf((xv[2]-m)*r*g0[2] + b0[2]);
    o[3] = (short)f2bf((xv[3]-m)*r*g0[3] + b0[3]);
    o[4] = (short)f2bf((xv[4]-m)*r*g1[0] + b1[0]);
    o[5] = (short)f2bf((xv[5]-m)*r*g1[1] + b1[1]);
    o[6] = (short)f2bf((xv[6]-m)*r*g1[2] + b1[2]);
    o[7] = (short)f2bf((xv[7]-m)*r*g1[3] + b1[3]);
    *(short8_t*)&out[(size_t)row*DIM + lane*8] = o;
}

// ---------------------------------------------------------------------------
// Fully fused attention per batch b (512 threads = 8 waves):
//  (a) wave h computes S_h = softmax_k(Q_h K_h^T / 8) via MFMA -> s_lds [208][28]
//  (b) vw[k,r] = sum_d2 V[k,r*64+d2]*sw[d2]   (416 threads, shfl-pair reduce)
//  (c) e[hq,r] = sum_k s*vw; comp = softmax_r(e)   (qv & score_b cancel)
//  (d) o[(h,q),d2] = sum_kr (s*comp) @ Vflat  via MFMA (K=208 pad 224)
__global__ __launch_bounds__(512) void attn_fused_kernel(const u16* __restrict__ qkv,
                                                         const float* __restrict__ score_w,
                                                         u16* __restrict__ attn_o) {
    int b = blockIdx.x;
    __shared__ u16 Bt[64*224];        // V as [d2][kr], byte ^= (d2&7)<<4
    __shared__ float s_lds[208*28];   // [(h*26+q)][k], k 26..27 = 0
    __shared__ float vwl[208];        // [k*8+r]
    __shared__ float cmp_lds[208*8];  // [(h,q)][r]
    __shared__ float swl[64];
    int tid = threadIdx.x;
    int lane = tid & 63, w = tid >> 6;

    if (tid < 64) swl[tid] = score_w[32 + tid];
    // V -> Bt (transpose to [d2][kr]); coalesced global bf16 reads
    for (int k = 0; k < 26; ++k) {
        int d2 = tid & 63, r = tid >> 6;
        u16 v = qkv[(size_t)(b*SEQ+k)*1536 + 1024 + tid];
        int bo = (d2*448 + (k*8+r)*2) ^ ((d2 & 7) << 4);
        *(u16*)((char*)Bt + bo) = v;
    }
    {   // zero-pad kr 208..223
        int d2 = tid & 63, kr = 208 + (tid >> 6);
        int bo1 = (d2*448 + kr*2)     ^ ((d2 & 7) << 4);
        int bo2 = (d2*448 + (kr+8)*2) ^ ((d2 & 7) << 4);
        *(u16*)((char*)Bt + bo1) = 0;
        *(u16*)((char*)Bt + bo2) = 0;
    }
    // zero-pad s_lds cols 26,27
    for (int row = tid; row < 208; row += 512) {
        s_lds[row*28 + 26] = 0.f; s_lds[row*28 + 27] = 0.f;
    }

    // ---- (a) QK^T + softmax, wave w handles head h=w ----
    {
        int h = w;
        int col16 = lane & 15, ch = lane >> 4;
        short8_t qf[2][2], kf[2][2];
        #pragma unroll
        for (int mi = 0; mi < 2; ++mi) {
            int q = mi*16 + col16;
            #pragma unroll
            for (int kk = 0; kk < 2; ++kk) {
                if (q < 26)
                    qf[mi][kk] = *(const short8_t*)&qkv[(size_t)(b*SEQ+q)*1536 + h*64 + kk*32 + ch*8];
                else
                    qf[mi][kk] = (short8_t){0,0,0,0,0,0,0,0};
            }
        }
        #pragma unroll
        for (int ni = 0; ni < 2; ++ni) {
            int kq = ni*16 + col16;
            #pragma unroll
            for (int kk = 0; kk < 2; ++kk) {
                if (kq < 26)
                    kf[ni][kk] = *(const short8_t*)&qkv[(size_t)(b*SEQ+kq)*1536 + 512 + h*64 + kk*32 + ch*8];
                else
                    kf[ni][kk] = (short8_t){0,0,0,0,0,0,0,0};
            }
        }
        floatx4 sacc[2][2];
        #pragma unroll
        for (int mi = 0; mi < 2; ++mi)
            #pragma unroll
            for (int ni = 0; ni < 2; ++ni)
                sacc[mi][ni] = (floatx4){0.f,0.f,0.f,0.f};
        #pragma unroll
        for (int kk = 0; kk < 2; ++kk)
            #pragma unroll
            for (int mi = 0; mi < 2; ++mi)
                #pragma unroll
                for (int ni = 0; ni < 2; ++ni)
                    sacc[mi][ni] = __builtin_amdgcn_mfma_f32_16x16x32_bf16(
                        qf[mi][kk], kf[ni][kk], sacc[mi][ni], 0, 0, 0);
        #pragma unroll
        for (int mi = 0; mi < 2; ++mi) {
            #pragma unroll
            for (int r = 0; r < 4; ++r) {
                float s0 = sacc[mi][0][r] * 0.125f;
                float s1 = (col16 < 10) ? sacc[mi][1][r] * 0.125f : -1e30f;
                float mx = fmaxf(s0, s1);
                #pragma unroll
                for (int msk = 1; msk < 16; msk <<= 1) mx = fmaxf(mx, __shfl_xor(mx, msk));
                float e0 = __expf(s0 - mx);
                float e1 = (col16 < 10) ? __expf(s1 - mx) : 0.f;
                float den = e0 + e1;
                #pragma unroll
                for (int msk = 1; msk < 16; msk <<= 1) den += __shfl_xor(den, msk);
                float inv = 1.f / den;
                int q = mi*16 + ch*4 + r;
                if (q < 26) {
                    s_lds[(h*26+q)*28 + col16] = e0 * inv;
                    if (col16 < 10) s_lds[(h*26+q)*28 + 16 + col16] = e1 * inv;
                }
            }
        }
    }
    __syncthreads();

    // ---- (b) vw: 416 threads, each sums half the d2 range; pair-reduce ----
    if (tid < 416) {
        int kr = tid >> 1, h0 = (tid & 1) * 32;
        float acc = 0.f;
        #pragma unroll
        for (int dd = 0; dd < 32; ++dd) {
            int d2 = h0 + dd;
            int bo = (d2*448 + kr*2) ^ ((d2 & 7) << 4);
            acc += bf2f(*(const u16*)((const char*)Bt + bo)) * swl[d2];
        }
        acc += __shfl_xor(acc, 1);
        if ((tid & 1) == 0) vwl[kr] = acc;
    }
    __syncthreads();

    // ---- (c) e + softmax over r ----
    if (tid < 208) {
        float srow[26];
        #pragma unroll
        for (int k = 0; k < 26; ++k) srow[k] = s_lds[tid*28 + k];
        float e[8];
        #pragma unroll
        for (int r = 0; r < 8; ++r) {
            float a = 0.f;
            #pragma unroll
            for (int k = 0; k < 26; ++k) a += srow[k] * vwl[k*8 + r];
            e[r] = a;
        }
        float m = e[0];
        #pragma unroll
        for (int r = 1; r < 8; ++r) m = fmaxf(m, e[r]);
        float den = 0.f;
        #pragma unroll
        for (int r = 0; r < 8; ++r) { e[r] = __expf(e[r]-m); den += e[r]; }
        float inv = 1.f/den;
        #pragma unroll
        for (int r = 0; r < 8; ++r) cmp_lds[tid*8+r] = e[r]*inv;
    }
    __syncthreads();

    // ---- (d) MFMA: C[208][64] = w2[208][224] @ Vflat[224][64] ----
    int mh = w >> 2, nt = w & 3;
    int ntile0 = nt*16;
    short8_t bfr[7];
    #pragma unroll
    for (int ks = 0; ks < 7; ++ks) {
        int col = ntile0 + (lane & 15);
        int krb = ks*32 + (lane >> 4)*8;
        int bo = (col*448 + krb*2) ^ ((col & 7) << 4);
        bfr[ks] = *(const short8_t*)((const char*)Bt + bo);
    }
    int mt0 = mh ? 7 : 0, mt1 = mh ? 13 : 7;
    for (int mt = mt0; mt < mt1; ++mt) {
        int arow = mt*16 + (lane & 15);
        float c8[8];
        #pragma unroll
        for (int r = 0; r < 8; ++r) c8[r] = cmp_lds[arow*8 + r];
        floatx4 acc = (floatx4){0.f,0.f,0.f,0.f};
        #pragma unroll
        for (int ks = 0; ks < 7; ++ks) {
            int k = ks*4 + (lane >> 4);
            float sv = s_lds[arow*28 + k];
            short8_t af;
            #pragma unroll
            for (int j = 0; j < 8; ++j) af[j] = (short)f2bf(sv * c8[j]);
            acc = __builtin_amdgcn_mfma_f32_16x16x32_bf16(af, bfr[ks], acc, 0, 0, 0);
        }
        int colg = ntile0 + (lane & 15);
        #pragma unroll
        for (int rr = 0; rr < 4; ++rr) {
            int rowg = mt*16 + (lane >> 4)*4 + rr;
            int h = rowg / 26, q = rowg - h*26;
            attn_o[(size_t)(b*SEQ+q)*DIM + h*64 + colg] = f2bf(acc[rr]);
        }
    }
}

// ---------------------------------------------------------------------------
// head: y = x[:,0,:]@out_w+out_b; log_softmax. grid B, block 256, d-parallel.
// x is bf16.
__global__ void head_kernel(const u16* __restrict__ x, const float* __restrict__ out_w,
                            const float* __restrict__ out_b, float* __restrict__ y) {
    int b = blockIdx.x;
    int tid = threadIdx.x;
    const u16* xr = x + (size_t)(b*SEQ)*DIM;
    float x0 = bf2f(xr[tid]), x1 = bf2f(xr[tid+256]);
    float part[10];
    #pragma unroll
    for (int c = 0; c < 10; ++c)
        part[c] = x0*out_w[tid*10 + c] + x1*out_w[(tid+256)*10 + c];
    #pragma unroll
    for (int off = 32; off; off >>= 1)
        #pragma unroll
        for (int c = 0; c < 10; ++c) part[c] += __shfl_down(part[c], off);
    __shared__ float red[4][10];
    __shared__ float yv[10];
    int wid = tid >> 6, lane = tid & 63;
    if (lane == 0)
        #pragma unroll
        for (int c = 0; c < 10; ++c) red[wid][c] = part[c];
    __syncthreads();
    if (tid < 10)
        yv[tid] = out_b[tid] + red[0][tid] + red[1][tid] + red[2][tid] + red[3][tid];
    __syncthreads();
    if (tid < 10) {
        float m = yv[0];
        #pragma unroll
        for (int i = 1; i < 10; ++i) m = fmaxf(m, yv[i]);
        float den = 0.0f;
        #pragma unroll
        for (int i = 0; i < 10; ++i) den += __expf(yv[i]-m);
        y[b*10 + tid] = yv[tid] - m - __logf(den);
    }
}

// ---------------------------------------------------------------------------
extern "C" void kernel_launch(void* const* d_in, const int* in_sizes, int n_in,
                              void* d_out, int out_size, void* d_ws, size_t ws_size,
                              hipStream_t stream) {
    const float* img      = (const float*)d_in[0];
    const float* qst      = (const float*)d_in[1];
    const float* conv_w   = (const float*)d_in[2];
    const float* conv_b   = (const float*)d_in[3];
    const float* qrep_w   = (const float*)d_in[4];
    const float* qrep_b   = (const float*)d_in[5];
    const float* cls_tok  = (const float*)d_in[6];
    const float* map_w    = (const float*)d_in[7];
    const float* map_b    = (const float*)d_in[8];
    const float* norm1_g  = (const float*)d_in[9];
    const float* norm1_b  = (const float*)d_in[10];
    const float* norm2_g  = (const float*)d_in[11];
    const float* norm2_b  = (const float*)d_in[12];
    const float* q_w      = (const float*)d_in[13];
    const float* q_b      = (const float*)d_in[14];
    const float* k_w      = (const float*)d_in[15];
    const float* k_b      = (const float*)d_in[16];
    const float* v_w      = (const float*)d_in[17];
    const float* v_b      = (const float*)d_in[18];
    // d_in[19] qv_w, d_in[20] qv_b: cancel in r-softmax — unused
    const float* score_w  = (const float*)d_in[21];
    // d_in[22] score_b: constant along softmax axis — unused
    const float* final_w  = (const float*)d_in[23];
    const float* final_b  = (const float*)d_in[24];
    const float* ffn1_w   = (const float*)d_in[25];
    const float* ffn1_b   = (const float*)d_in[26];
    const float* ffn2_w   = (const float*)d_in[27];
    const float* ffn2_b   = (const float*)d_in[28];
    const float* out_w    = (const float*)d_in[29];
    const float* out_b    = (const float*)d_in[30];

    float* ws = (float*)d_ws;
    size_t o = 0;
    u16* x      = (u16*)(ws+o); o += (size_t)TOK*DIM/2;    // bf16 residual stream
    u16* qkvT   = (u16*)(ws+o); o += (size_t)1536*512/2;
    u16* finT   = (u16*)(ws+o); o += (size_t)512*512/2;
    u16* f1T    = (u16*)(ws+o); o += (size_t)1024*512/2;
    u16* f2T    = (u16*)(ws+o); o += (size_t)512*1024/2;
    u16* mapT   = (u16*)(ws+o); o += (size_t)512*256/2;
    u16* cwT    = (u16*)(ws+o); o += (size_t)256*704/2;
    float* qkvb = ws + o;       o += 1536;
    float* r2   = ws + o;
    // phase-2 layout in r2
    u16*  h_bf    = (u16*)r2;                                  // TOK*512 bf16
    u16*  qkv_bf  = (u16*)(r2 + (size_t)TOK*DIM/2);            // TOK*1536 bf16
    u16*  attn_obf= (u16*)(r2 + (size_t)TOK*DIM/2 + (size_t)TOK*1536/2); // TOK*512 bf16
    u16*  ffbuf   = qkv_bf;                                    // alias (qkv dead in FFN)
    // phase-1 aliases r2
    u16*  Pbuf    = (u16*)r2;                                  // 6400*704 bf16
    u16*  emb_bf  = (u16*)(r2 + (size_t)6400*704/2);           // TOK*256 bf16
    float* quem   = r2 + (size_t)6400*704/2 + (size_t)TOK*256/2;

    // ---- weight prep + cls rows + question path: one dispatch ----
    prep_all<<<1313, 256, 0, stream>>>(q_w, k_w, v_w, final_w, ffn1_w, ffn2_w, map_w, conv_w,
                                       q_b, k_b, v_b, cls_tok, qst, qrep_w, qrep_b, map_b,
                                       qkvT, finT, f1T, f2T, mapT, cwT, qkvb, emb_bf, quem);

    // ---- phase 1: embedding ----
    im2col_kernel<<<6400, 256, 0, stream>>>(img, Pbuf);
    // conv patch-GEMM writes emb rows directly (+pe), bf16
    mfma_gemm<64,3,0,1><<<dim3(2,100), dim3(512), 0, stream>>>(
        Pbuf, cwT, conv_b, nullptr, emb_bf, 6400, 256, 704, 1.0f);
    // x (bf16) = emb @ map_w[:256] + quem (f32 per-batch)
    mfma_gemm<64,2,0,1><<<dim3(4,104), dim3(512), 0, stream>>>(
        emb_bf, mapT, nullptr, quem, x, TOK, 512, 256, 1.0f);

    // ---- phase 2: 4 transformer iterations ----
    for (int it = 0; it < 4; ++it) {
        ln_kernel<<<TOK/4, 256, 0, stream>>>(x, norm1_g, norm1_b, h_bf);
        mfma_gemm<128,0,0,1><<<dim3(12,52), dim3(512), 0, stream>>>(
            h_bf, qkvT, qkvb, nullptr, qkv_bf, TOK, 1536, 512, 1.0f);
        attn_fused_kernel<<<NB, 512, 0, stream>>>(qkv_bf, score_w, attn_obf);
        mfma_gemm<64,1,0,1><<<dim3(4,104), dim3(512), 0, stream>>>(
            attn_obf, finT, final_b, x, x, TOK, 512, 512, 1.0f);
        ln_kernel<<<TOK/4, 256, 0, stream>>>(x, norm2_g, norm2_b, h_bf);
        mfma_gemm<128,0,1,1><<<dim3(8,52), dim3(512), 0, stream>>>(
            h_bf, f1T, ffn1_b, nullptr, ffbuf, TOK, 1024, 512, 1.0f);
        mfma_gemm<64,1,0,1><<<dim3(4,104), dim3(512), 0, stream>>>(
            ffbuf, f2T, ffn2_b, x, x, TOK, 512, 1024, 1.0f);
    }

    head_kernel<<<NB, 256, 0, stream>>>(x, out_w, out_b, (float*)d_out);
}